// Round 5
// baseline (199.265 us; speedup 1.0000x reference)
//
#include <hip/hip_runtime.h>
#include <hip/hip_fp16.h>
#include <math.h>

// SPAIRPointFeatureNetwork on MI355X.
//   h_{p,j} = Q[j] - G[p];  celu monotonic => segmax(celu(h)) = celu(max_j Q[j] - G[p]).
// Per-edge work = gather fp16 Q row + packed-fp16 running max.
//
// R4 post-mortem: edge kernels are L1-miss/MSHR-latency bound (random rows in a
// 4 MB table, 0% L1 hit). R5: spatial cell-sort. Q tables stored and processed
// in cell-sorted order -> a wave's 4 points share one cell and ~2/3 of their
// neighbor rows; L1 hits eliminate MSHR occupancy. max is order-invariant and
// fp16-exact, so any permutation is bit-identical.

#define NPTS 65536
#define KNBR 64
#define GRES 16
#define NCELL 4096   // 16^3

__device__ __forceinline__ float celu1(float x) {
    return x > 0.0f ? x : (__expf(x) - 1.0f);
}

__device__ __forceinline__ unsigned pkmax(unsigned a, unsigned b) {
    unsigned d;
    asm("v_pk_max_f16 %0, %1, %2" : "=v"(d) : "v"(a), "v"(b));
    return d;
}

__device__ __forceinline__ unsigned pack2(float a, float b) {
    __half2 h = __floats2half2_rn(a, b);
    return *(unsigned*)&h;
}

__device__ __forceinline__ int cell_of(float p0, float p1, float p2) {
    int cx = min((int)(p0 * 16.0f), 15);
    int cy = min((int)(p1 * 16.0f), 15);
    int cz = min((int)(p2 * 16.0f), 15);
    return (cx * GRES + cy) * GRES + cz;
}

// ---- sort pipeline ----

__global__ __launch_bounds__(256) void k_zero(int* __restrict__ buf) {
    buf[blockIdx.x * 256 + threadIdx.x] = 0;   // counts + cursor: 2*NCELL ints
}

__global__ __launch_bounds__(256) void k_hist(
    const float* __restrict__ pos, int* __restrict__ counts)
{
    int t = blockIdx.x * 256 + threadIdx.x;
    if (t >= NPTS) return;
    int cid = cell_of(pos[3 * t], pos[3 * t + 1], pos[3 * t + 2]);
    atomicAdd(&counts[cid], 1);
}

// single wave: exclusive scan of 4096 counts -> starts
__global__ void k_scan(const int* __restrict__ counts, int* __restrict__ starts) {
    int lane = threadIdx.x;             // 0..63, 64 cells each
    const int4* cp = (const int4*)counts;
    int4 c[16];
#pragma unroll
    for (int k = 0; k < 16; ++k) c[k] = cp[lane * 16 + k];
    int T = 0;
#pragma unroll
    for (int k = 0; k < 16; ++k) T += c[k].x + c[k].y + c[k].z + c[k].w;
    int inc = T;
#pragma unroll
    for (int d = 1; d < 64; d <<= 1) {
        int u = __shfl_up(inc, d, 64);
        if (lane >= d) inc += u;
    }
    int run = inc - T;                  // exclusive base for this lane's chunk
    int4* sp = (int4*)starts;
#pragma unroll
    for (int k = 0; k < 16; ++k) {
        int4 v = c[k], o;
        o.x = run; run += v.x;
        o.y = run; run += v.y;
        o.z = run; run += v.z;
        o.w = run; run += v.w;
        sp[lane * 16 + k] = o;
    }
}

// slot assignment + sorted pos + sorted Q1 (fp16) + d_out pos copy + batch zeros
__global__ __launch_bounds__(256) void k_slot(
    const float* __restrict__ pos,
    const int* __restrict__ starts, int* __restrict__ cursor,
    int* __restrict__ slot_of, int* __restrict__ perm,
    float* __restrict__ pos_s,
    const float* __restrict__ w1a, const float* __restrict__ b1a,
    __half* __restrict__ q1,
    float* __restrict__ dout, int out_size)
{
    int t = blockIdx.x * 256 + threadIdx.x;
    if (t >= NPTS) return;
    float p0 = pos[3 * t + 0];
    float p1 = pos[3 * t + 1];
    float p2 = pos[3 * t + 2];
    dout[3 * t + 0] = p0;
    dout[3 * t + 1] = p1;
    dout[3 * t + 2] = p2;
    for (int j = 35 * NPTS + t; j < out_size; j += NPTS)
        dout[j] = 0.0f;

    int cid = cell_of(p0, p1, p2);
    int s = starts[cid] + atomicAdd(&cursor[cid], 1);
    slot_of[t] = s;
    perm[s] = t;
    pos_s[3 * s + 0] = p0;
    pos_s[3 * s + 1] = p1;
    pos_s[3 * s + 2] = p2;

    float q[8];
#pragma unroll
    for (int c = 0; c < 8; ++c) {
        float a = b1a[c];
        a = fmaf(p0, w1a[0 * 8 + c] + w1a[3 * 8 + c], a);
        a = fmaf(p1, w1a[1 * 8 + c] + w1a[4 * 8 + c], a);
        a = fmaf(p2, w1a[2 * 8 + c] + w1a[5 * 8 + c], a);
        q[c] = a;
    }
    uint4 pk;
    pk.x = pack2(q[0], q[1]);
    pk.y = pack2(q[2], q[3]);
    pk.z = pack2(q[4], q[5]);
    pk.w = pack2(q[6], q[7]);
    *(uint4*)(q1 + 8 * s) = pk;
}

// edge-list remap into sorted space: one wave per sorted row
__global__ __launch_bounds__(256) void k_remap(
    const int* __restrict__ idx,       // original N x 64
    const int* __restrict__ perm,
    const int* __restrict__ slot_of,
    int* __restrict__ idxs)            // sorted+remapped N x 64
{
    int w = (blockIdx.x * 256 + threadIdx.x) >> 6;
    int k = threadIdx.x & 63;
    int src = perm[w];
    int j = idx[src * 64 + k];         // coalesced 256B row read
    idxs[w * 64 + k] = slot_of[j];     // small-table gather, coalesced store
}

// ---- edge kernel (row-parallel, packed fp16 max), sorted space ----
template <int FH>
__global__ __launch_bounds__(256) void k_edge(
    const __half* __restrict__ q,   // N x FH (fp16, sorted)
    const int* __restrict__ idx,    // N x 64 (sorted+remapped)
    __half* __restrict__ m)         // N x FH (fp16 segmax, sorted)
{
    constexpr int SL  = FH / 8;     // lanes per row
    constexpr int EG  = 16 / SL;    // edge groups per point
    constexpr int EPG = 64 / EG;    // edges per group (contiguous)

    int wave = (blockIdx.x * 256 + threadIdx.x) >> 6;
    int l  = threadIdx.x & 63;
    int pl = l >> 4;
    int u  = l & 15;
    int c  = u % SL;
    int g  = u / SL;
    int p  = wave * 4 + pl;

    const uint4* ip = (const uint4*)(idx + p * KNBR + g * EPG);
    uint4 iv[EPG / 4];
#pragma unroll
    for (int k = 0; k < EPG / 4; ++k) iv[k] = ip[k];

    unsigned ax = 0xFC00FC00u, ay = 0xFC00FC00u, az = 0xFC00FC00u, aw = 0xFC00FC00u;
#pragma unroll
    for (int k = 0; k < EPG / 4; ++k) {
        int j0 = (int)iv[k].x, j1 = (int)iv[k].y, j2 = (int)iv[k].z, j3 = (int)iv[k].w;
        uint4 v0 = *(const uint4*)(q + j0 * FH + c * 8);
        uint4 v1 = *(const uint4*)(q + j1 * FH + c * 8);
        uint4 v2 = *(const uint4*)(q + j2 * FH + c * 8);
        uint4 v3 = *(const uint4*)(q + j3 * FH + c * 8);
        ax = pkmax(ax, v0.x); ay = pkmax(ay, v0.y); az = pkmax(az, v0.z); aw = pkmax(aw, v0.w);
        ax = pkmax(ax, v1.x); ay = pkmax(ay, v1.y); az = pkmax(az, v1.z); aw = pkmax(aw, v1.w);
        ax = pkmax(ax, v2.x); ay = pkmax(ay, v2.y); az = pkmax(az, v2.z); aw = pkmax(aw, v2.w);
        ax = pkmax(ax, v3.x); ay = pkmax(ay, v3.y); az = pkmax(az, v3.z); aw = pkmax(aw, v3.w);
    }
#pragma unroll
    for (int st = SL; st < 16; st <<= 1) {
        ax = pkmax(ax, (unsigned)__shfl_xor((int)ax, st, 64));
        ay = pkmax(ay, (unsigned)__shfl_xor((int)ay, st, 64));
        az = pkmax(az, (unsigned)__shfl_xor((int)az, st, 64));
        aw = pkmax(aw, (unsigned)__shfl_xor((int)aw, st, 64));
    }
    if (g == 0) {
        uint4 r; r.x = ax; r.y = ay; r.z = az; r.w = aw;
        *(uint4*)(m + p * FH + c * 8) = r;
    }
}

// ---- finish (sorted space): agg = celu(m - G), x = celu(agg@wb + bb) ----
template <int FH, int FOUT, int FHN, bool WRITEX>
__global__ __launch_bounds__(256) void k_finish(
    const __half* __restrict__ m,    // N x FH (fp16, sorted)
    const float* __restrict__ pos_s,
    const float* __restrict__ wap,   // 3 x FH
    const float* __restrict__ wb,    // FH x FOUT
    const float* __restrict__ bb,    // FOUT
    const float* __restrict__ wan,   // (FOUT+3) x FHN or null
    const float* __restrict__ ban,   // FHN or null
    const int* __restrict__ perm,    // sorted -> original (for WRITEX scatter)
    float* __restrict__ xout,        // base of x region (only if WRITEX)
    __half* __restrict__ qnext)      // N x FHN fp16 sorted (only if FHN>0)
{
    int t = blockIdx.x * 256 + threadIdx.x;
    float p0 = pos_s[3 * t + 0];
    float p1 = pos_s[3 * t + 1];
    float p2 = pos_s[3 * t + 2];

    float h[FH];
    const uint4* mr = (const uint4*)(m + t * FH);
#pragma unroll
    for (int l = 0; l < FH / 8; ++l) {
        uint4 v = mr[l];
        unsigned w4[4] = {v.x, v.y, v.z, v.w};
#pragma unroll
        for (int k = 0; k < 4; ++k) {
            float2 f = __half22float2(*(__half2*)&w4[k]);
            h[l * 8 + k * 2 + 0] = f.x;
            h[l * 8 + k * 2 + 1] = f.y;
        }
    }
#pragma unroll
    for (int c = 0; c < FH; ++c) {
        float g = p0 * wap[c] + p1 * wap[FH + c] + p2 * wap[2 * FH + c];
        h[c] = celu1(h[c] - g);
    }
    float x[FOUT];
#pragma unroll
    for (int c2 = 0; c2 < FOUT; ++c2) {
        float a = bb[c2];
#pragma unroll
        for (int c = 0; c < FH; ++c)
            a = fmaf(h[c], wb[c * FOUT + c2], a);
        x[c2] = celu1(a);
    }
    if constexpr (WRITEX) {
        int orig = perm[t];
        float4* xo = (float4*)(xout + (long long)orig * FOUT);
#pragma unroll
        for (int c4 = 0; c4 < FOUT / 4; ++c4)
            xo[c4] = make_float4(x[4 * c4 + 0], x[4 * c4 + 1], x[4 * c4 + 2], x[4 * c4 + 3]);
    }
    if constexpr (FHN > 0) {
        float qn[FHN];
#pragma unroll
        for (int cn = 0; cn < FHN; ++cn) {
            float a = ban[cn];
#pragma unroll
            for (int c2 = 0; c2 < FOUT; ++c2)
                a = fmaf(x[c2], wan[c2 * FHN + cn], a);
            a = fmaf(p0, wan[(FOUT + 0) * FHN + cn], a);
            a = fmaf(p1, wan[(FOUT + 1) * FHN + cn], a);
            a = fmaf(p2, wan[(FOUT + 2) * FHN + cn], a);
            qn[cn] = a;
        }
        uint4* qo = (uint4*)(qnext + t * FHN);
#pragma unroll
        for (int l = 0; l < FHN / 8; ++l) {
            uint4 pk;
            pk.x = pack2(qn[l * 8 + 0], qn[l * 8 + 1]);
            pk.y = pack2(qn[l * 8 + 2], qn[l * 8 + 3]);
            pk.z = pack2(qn[l * 8 + 4], qn[l * 8 + 5]);
            pk.w = pack2(qn[l * 8 + 6], qn[l * 8 + 7]);
            qo[l] = pk;
        }
    }
}

extern "C" void kernel_launch(void* const* d_in, const int* in_sizes, int n_in,
                              void* d_out, int out_size, void* d_ws, size_t ws_size,
                              hipStream_t stream) {
    const float* pos = (const float*)d_in[0];
    // d_in[1] rgb (unused), d_in[2] batch (zeros), d_in[3] out_index (= repeat(arange(N),K))
    const int* idx = (const int*)d_in[4];   // in_index, int32 per harness contract
    const float* w1a = (const float*)d_in[5];
    const float* b1a = (const float*)d_in[6];
    const float* w1b = (const float*)d_in[7];
    const float* b1b = (const float*)d_in[8];
    const float* w2a = (const float*)d_in[9];
    const float* b2a = (const float*)d_in[10];
    const float* w2b = (const float*)d_in[11];
    const float* b2b = (const float*)d_in[12];
    const float* w3a = (const float*)d_in[13];
    const float* b3a = (const float*)d_in[14];
    const float* w3b = (const float*)d_in[15];
    const float* b3b = (const float*)d_in[16];
    float* out = (float*)d_out;

    char* ws = (char*)d_ws;
    int*    idxs    = (int*)ws;                                  // 16 MB
    __half* A       = (__half*)(ws + (16u << 20));               // 4 MB
    __half* B       = (__half*)(ws + (20u << 20));               // 4 MB
    float*  pos_s   = (float*)(ws + (24u << 20));                // 768 KB
    int*    slot_of = (int*)(ws + (25u << 20));                  // 256 KB
    int*    perm    = (int*)(ws + (25u << 20) + (256u << 10));   // 256 KB
    int*    counts  = (int*)(ws + (26u << 20));                  // 16 KB
    int*    cursor  = counts + NCELL;                            // 16 KB
    int*    starts  = cursor + NCELL;                            // 16 KB

    // sort pipeline
    k_zero<<<2 * NCELL / 256, 256, 0, stream>>>(counts);  // counts + cursor
    k_hist<<<NPTS / 256, 256, 0, stream>>>(pos, counts);
    k_scan<<<1, 64, 0, stream>>>(counts, starts);
    k_slot<<<NPTS / 256, 256, 0, stream>>>(pos, starts, cursor, slot_of, perm,
                                           pos_s, w1a, b1a, A, out, out_size);
    k_remap<<<NPTS / 4, 256, 0, stream>>>(idx, perm, slot_of, idxs);

    // layer 1
    k_edge<8><<<NPTS / 16, 256, 0, stream>>>(A, idxs, B);
    k_finish<8, 8, 16, false><<<NPTS / 256, 256, 0, stream>>>(
        B, pos_s, w1a + 3 * 8, w1b, b1b, w2a, b2a, perm, nullptr, A);
    // layer 2
    k_edge<16><<<NPTS / 16, 256, 0, stream>>>(A, idxs, B);
    k_finish<16, 16, 32, false><<<NPTS / 256, 256, 0, stream>>>(
        B, pos_s, w2a + 8 * 16, w2b, b2b, w3a, b3a, perm, nullptr, A);
    // layer 3
    k_edge<32><<<NPTS / 16, 256, 0, stream>>>(A, idxs, B);
    k_finish<32, 32, 0, true><<<NPTS / 256, 256, 0, stream>>>(
        B, pos_s, w3a + 16 * 32, w3b, b3b, nullptr, nullptr, perm, out + 3 * NPTS, nullptr);
}

// Round 6
// 199.227 us; speedup vs baseline: 1.0002x; 1.0002x over previous
//
#include <hip/hip_runtime.h>
#include <hip/hip_fp16.h>
#include <math.h>

// SPAIRPointFeatureNetwork on MI355X.
//   h_{p,j} = Q[j] - G[p];  celu monotonic => segmax(celu(h)) = celu(max_j Q[j] - G[p]).
// Per-edge work = gather fp16 Q row + packed-fp16 running max.
//
// R5 post-mortem: k_edge VGPR_Count=32 -> compiler held only ~2-4 gathers in
// flight; kernels were MLP-starved (latency-serialized), which is why both
// coalescing (R4) and cell-sort locality (R5) underdelivered. R6: explicit
// 8-deep load batching per lane (distinct registers, loads issued before any
// consumption) -> ~256 outstanding loads/CU at full occupancy.

#define NPTS 65536
#define KNBR 64
#define GRES 16
#define NCELL 4096   // 16^3

__device__ __forceinline__ float celu1(float x) {
    return x > 0.0f ? x : (__expf(x) - 1.0f);
}

__device__ __forceinline__ unsigned pkmax(unsigned a, unsigned b) {
    unsigned d;
    asm("v_pk_max_f16 %0, %1, %2" : "=v"(d) : "v"(a), "v"(b));
    return d;
}

__device__ __forceinline__ unsigned pack2(float a, float b) {
    __half2 h = __floats2half2_rn(a, b);
    return *(unsigned*)&h;
}

__device__ __forceinline__ int cell_of(float p0, float p1, float p2) {
    int cx = min((int)(p0 * 16.0f), 15);
    int cy = min((int)(p1 * 16.0f), 15);
    int cz = min((int)(p2 * 16.0f), 15);
    return (cx * GRES + cy) * GRES + cz;
}

// ---- sort pipeline ----

__global__ __launch_bounds__(256) void k_zero(int* __restrict__ buf) {
    buf[blockIdx.x * 256 + threadIdx.x] = 0;   // counts + cursor: 2*NCELL ints
}

__global__ __launch_bounds__(256) void k_hist(
    const float* __restrict__ pos, int* __restrict__ counts)
{
    int t = blockIdx.x * 256 + threadIdx.x;
    if (t >= NPTS) return;
    int cid = cell_of(pos[3 * t], pos[3 * t + 1], pos[3 * t + 2]);
    atomicAdd(&counts[cid], 1);
}

// single wave: exclusive scan of 4096 counts -> starts
__global__ void k_scan(const int* __restrict__ counts, int* __restrict__ starts) {
    int lane = threadIdx.x;             // 0..63, 64 cells each
    const int4* cp = (const int4*)counts;
    int4 c[16];
#pragma unroll
    for (int k = 0; k < 16; ++k) c[k] = cp[lane * 16 + k];
    int T = 0;
#pragma unroll
    for (int k = 0; k < 16; ++k) T += c[k].x + c[k].y + c[k].z + c[k].w;
    int inc = T;
#pragma unroll
    for (int d = 1; d < 64; d <<= 1) {
        int u = __shfl_up(inc, d, 64);
        if (lane >= d) inc += u;
    }
    int run = inc - T;                  // exclusive base for this lane's chunk
    int4* sp = (int4*)starts;
#pragma unroll
    for (int k = 0; k < 16; ++k) {
        int4 v = c[k], o;
        o.x = run; run += v.x;
        o.y = run; run += v.y;
        o.z = run; run += v.z;
        o.w = run; run += v.w;
        sp[lane * 16 + k] = o;
    }
}

// slot assignment + sorted pos + sorted Q1 (fp16) + d_out pos copy + batch zeros
__global__ __launch_bounds__(256) void k_slot(
    const float* __restrict__ pos,
    const int* __restrict__ starts, int* __restrict__ cursor,
    int* __restrict__ slot_of, int* __restrict__ perm,
    float* __restrict__ pos_s,
    const float* __restrict__ w1a, const float* __restrict__ b1a,
    __half* __restrict__ q1,
    float* __restrict__ dout, int out_size)
{
    int t = blockIdx.x * 256 + threadIdx.x;
    if (t >= NPTS) return;
    float p0 = pos[3 * t + 0];
    float p1 = pos[3 * t + 1];
    float p2 = pos[3 * t + 2];
    dout[3 * t + 0] = p0;
    dout[3 * t + 1] = p1;
    dout[3 * t + 2] = p2;
    for (int j = 35 * NPTS + t; j < out_size; j += NPTS)
        dout[j] = 0.0f;

    int cid = cell_of(p0, p1, p2);
    int s = starts[cid] + atomicAdd(&cursor[cid], 1);
    slot_of[t] = s;
    perm[s] = t;
    pos_s[3 * s + 0] = p0;
    pos_s[3 * s + 1] = p1;
    pos_s[3 * s + 2] = p2;

    float q[8];
#pragma unroll
    for (int c = 0; c < 8; ++c) {
        float a = b1a[c];
        a = fmaf(p0, w1a[0 * 8 + c] + w1a[3 * 8 + c], a);
        a = fmaf(p1, w1a[1 * 8 + c] + w1a[4 * 8 + c], a);
        a = fmaf(p2, w1a[2 * 8 + c] + w1a[5 * 8 + c], a);
        q[c] = a;
    }
    uint4 pk;
    pk.x = pack2(q[0], q[1]);
    pk.y = pack2(q[2], q[3]);
    pk.z = pack2(q[4], q[5]);
    pk.w = pack2(q[6], q[7]);
    *(uint4*)(q1 + 8 * s) = pk;
}

// edge-list remap into sorted space: one wave per sorted row
__global__ __launch_bounds__(256) void k_remap(
    const int* __restrict__ idx,       // original N x 64
    const int* __restrict__ perm,
    const int* __restrict__ slot_of,
    int* __restrict__ idxs)            // sorted+remapped N x 64
{
    int w = (blockIdx.x * 256 + threadIdx.x) >> 6;
    int k = threadIdx.x & 63;
    int src = perm[w];
    int j = idx[src * 64 + k];         // coalesced 256B row read
    idxs[w * 64 + k] = slot_of[j];     // small-table gather, coalesced store
}

// ---- edge kernel: 8-deep explicit MLP ----
// Per point: LPP = FH/8*8 lanes; SL = FH/8 slice-lanes per row, 8 edge groups
// of 8 contiguous edges. Each lane loads its 8 row-slices into DISTINCT
// registers (all issued before first use), then pkmax tree + butterfly.
template <int FH>
__global__ __launch_bounds__(256) void k_edge(
    const __half* __restrict__ q,   // N x FH (fp16, sorted)
    const int* __restrict__ idx,    // N x 64 (sorted+remapped)
    __half* __restrict__ m)         // N x FH (fp16 segmax, sorted)
{
    constexpr int SL  = FH / 8;     // lanes per row (1,2,4)
    constexpr int LPP = SL * 8;     // lanes per point (8,16,32)
    constexpr int PPW = 64 / LPP;   // points per wave (8,4,2)

    int wave = (blockIdx.x * 256 + threadIdx.x) >> 6;
    int l  = threadIdx.x & 63;
    int pl = l / LPP;
    int u  = l % LPP;
    int c  = u % SL;                // 16B slice within row
    int g  = u / SL;                // edge group 0..7
    int p  = wave * PPW + pl;

    // 8 contiguous edge indices for this lane's group
    const uint4* ip = (const uint4*)(idx + p * KNBR + g * 8);
    uint4 i0 = ip[0];
    uint4 i1 = ip[1];

    // all 8 row-slice loads issued back-to-back (distinct destinations)
    uint4 v[8];
    v[0] = *(const uint4*)(q + (int)i0.x * FH + c * 8);
    v[1] = *(const uint4*)(q + (int)i0.y * FH + c * 8);
    v[2] = *(const uint4*)(q + (int)i0.z * FH + c * 8);
    v[3] = *(const uint4*)(q + (int)i0.w * FH + c * 8);
    v[4] = *(const uint4*)(q + (int)i1.x * FH + c * 8);
    v[5] = *(const uint4*)(q + (int)i1.y * FH + c * 8);
    v[6] = *(const uint4*)(q + (int)i1.z * FH + c * 8);
    v[7] = *(const uint4*)(q + (int)i1.w * FH + c * 8);

    unsigned ax = 0xFC00FC00u, ay = 0xFC00FC00u, az = 0xFC00FC00u, aw = 0xFC00FC00u;
#pragma unroll
    for (int k = 0; k < 8; ++k) {
        ax = pkmax(ax, v[k].x);
        ay = pkmax(ay, v[k].y);
        az = pkmax(az, v[k].z);
        aw = pkmax(aw, v[k].w);
    }
    // butterfly across the 8 edge groups (strides SL..LPP/2 stay inside point)
#pragma unroll
    for (int st = SL; st < LPP; st <<= 1) {
        ax = pkmax(ax, (unsigned)__shfl_xor((int)ax, st, 64));
        ay = pkmax(ay, (unsigned)__shfl_xor((int)ay, st, 64));
        az = pkmax(az, (unsigned)__shfl_xor((int)az, st, 64));
        aw = pkmax(aw, (unsigned)__shfl_xor((int)aw, st, 64));
    }
    if (g == 0) {
        uint4 r; r.x = ax; r.y = ay; r.z = az; r.w = aw;
        *(uint4*)(m + p * FH + c * 8) = r;
    }
}

// ---- finish (sorted space): agg = celu(m - G), x = celu(agg@wb + bb) ----
template <int FH, int FOUT, int FHN, bool WRITEX>
__global__ __launch_bounds__(256) void k_finish(
    const __half* __restrict__ m,    // N x FH (fp16, sorted)
    const float* __restrict__ pos_s,
    const float* __restrict__ wap,   // 3 x FH
    const float* __restrict__ wb,    // FH x FOUT
    const float* __restrict__ bb,    // FOUT
    const float* __restrict__ wan,   // (FOUT+3) x FHN or null
    const float* __restrict__ ban,   // FHN or null
    const int* __restrict__ perm,    // sorted -> original (for WRITEX scatter)
    float* __restrict__ xout,        // base of x region (only if WRITEX)
    __half* __restrict__ qnext)      // N x FHN fp16 sorted (only if FHN>0)
{
    int t = blockIdx.x * 256 + threadIdx.x;
    float p0 = pos_s[3 * t + 0];
    float p1 = pos_s[3 * t + 1];
    float p2 = pos_s[3 * t + 2];

    float h[FH];
    const uint4* mr = (const uint4*)(m + t * FH);
#pragma unroll
    for (int l = 0; l < FH / 8; ++l) {
        uint4 v = mr[l];
        unsigned w4[4] = {v.x, v.y, v.z, v.w};
#pragma unroll
        for (int k = 0; k < 4; ++k) {
            float2 f = __half22float2(*(__half2*)&w4[k]);
            h[l * 8 + k * 2 + 0] = f.x;
            h[l * 8 + k * 2 + 1] = f.y;
        }
    }
#pragma unroll
    for (int c = 0; c < FH; ++c) {
        float g = p0 * wap[c] + p1 * wap[FH + c] + p2 * wap[2 * FH + c];
        h[c] = celu1(h[c] - g);
    }
    float x[FOUT];
#pragma unroll
    for (int c2 = 0; c2 < FOUT; ++c2) {
        float a = bb[c2];
#pragma unroll
        for (int c = 0; c < FH; ++c)
            a = fmaf(h[c], wb[c * FOUT + c2], a);
        x[c2] = celu1(a);
    }
    if constexpr (WRITEX) {
        int orig = perm[t];
        float4* xo = (float4*)(xout + (long long)orig * FOUT);
#pragma unroll
        for (int c4 = 0; c4 < FOUT / 4; ++c4)
            xo[c4] = make_float4(x[4 * c4 + 0], x[4 * c4 + 1], x[4 * c4 + 2], x[4 * c4 + 3]);
    }
    if constexpr (FHN > 0) {
        float qn[FHN];
#pragma unroll
        for (int cn = 0; cn < FHN; ++cn) {
            float a = ban[cn];
#pragma unroll
            for (int c2 = 0; c2 < FOUT; ++c2)
                a = fmaf(x[c2], wan[c2 * FHN + cn], a);
            a = fmaf(p0, wan[(FOUT + 0) * FHN + cn], a);
            a = fmaf(p1, wan[(FOUT + 1) * FHN + cn], a);
            a = fmaf(p2, wan[(FOUT + 2) * FHN + cn], a);
            qn[cn] = a;
        }
        uint4* qo = (uint4*)(qnext + t * FHN);
#pragma unroll
        for (int l = 0; l < FHN / 8; ++l) {
            uint4 pk;
            pk.x = pack2(qn[l * 8 + 0], qn[l * 8 + 1]);
            pk.y = pack2(qn[l * 8 + 2], qn[l * 8 + 3]);
            pk.z = pack2(qn[l * 8 + 4], qn[l * 8 + 5]);
            pk.w = pack2(qn[l * 8 + 6], qn[l * 8 + 7]);
            qo[l] = pk;
        }
    }
}

extern "C" void kernel_launch(void* const* d_in, const int* in_sizes, int n_in,
                              void* d_out, int out_size, void* d_ws, size_t ws_size,
                              hipStream_t stream) {
    const float* pos = (const float*)d_in[0];
    // d_in[1] rgb (unused), d_in[2] batch (zeros), d_in[3] out_index (= repeat(arange(N),K))
    const int* idx = (const int*)d_in[4];   // in_index, int32 per harness contract
    const float* w1a = (const float*)d_in[5];
    const float* b1a = (const float*)d_in[6];
    const float* w1b = (const float*)d_in[7];
    const float* b1b = (const float*)d_in[8];
    const float* w2a = (const float*)d_in[9];
    const float* b2a = (const float*)d_in[10];
    const float* w2b = (const float*)d_in[11];
    const float* b2b = (const float*)d_in[12];
    const float* w3a = (const float*)d_in[13];
    const float* b3a = (const float*)d_in[14];
    const float* w3b = (const float*)d_in[15];
    const float* b3b = (const float*)d_in[16];
    float* out = (float*)d_out;

    char* ws = (char*)d_ws;
    int*    idxs    = (int*)ws;                                  // 16 MB
    __half* A       = (__half*)(ws + (16u << 20));               // 4 MB
    __half* B       = (__half*)(ws + (20u << 20));               // 4 MB
    float*  pos_s   = (float*)(ws + (24u << 20));                // 768 KB
    int*    slot_of = (int*)(ws + (25u << 20));                  // 256 KB
    int*    perm    = (int*)(ws + (25u << 20) + (256u << 10));   // 256 KB
    int*    counts  = (int*)(ws + (26u << 20));                  // 16 KB
    int*    cursor  = counts + NCELL;                            // 16 KB
    int*    starts  = cursor + NCELL;                            // 16 KB

    // sort pipeline
    k_zero<<<2 * NCELL / 256, 256, 0, stream>>>(counts);  // counts + cursor
    k_hist<<<NPTS / 256, 256, 0, stream>>>(pos, counts);
    k_scan<<<1, 64, 0, stream>>>(counts, starts);
    k_slot<<<NPTS / 256, 256, 0, stream>>>(pos, starts, cursor, slot_of, perm,
                                           pos_s, w1a, b1a, A, out, out_size);
    k_remap<<<NPTS / 4, 256, 0, stream>>>(idx, perm, slot_of, idxs);

    // layer 1  (FH=8: 8 points/wave -> 32 pts/block)
    k_edge<8><<<NPTS / 32, 256, 0, stream>>>(A, idxs, B);
    k_finish<8, 8, 16, false><<<NPTS / 256, 256, 0, stream>>>(
        B, pos_s, w1a + 3 * 8, w1b, b1b, w2a, b2a, perm, nullptr, A);
    // layer 2  (FH=16: 4 points/wave -> 16 pts/block)
    k_edge<16><<<NPTS / 16, 256, 0, stream>>>(A, idxs, B);
    k_finish<16, 16, 32, false><<<NPTS / 256, 256, 0, stream>>>(
        B, pos_s, w2a + 8 * 16, w2b, b2b, w3a, b3a, perm, nullptr, A);
    // layer 3  (FH=32: 2 points/wave -> 8 pts/block)
    k_edge<32><<<NPTS / 8, 256, 0, stream>>>(A, idxs, B);
    k_finish<32, 32, 0, true><<<NPTS / 256, 256, 0, stream>>>(
        B, pos_s, w3a + 16 * 32, w3b, b3b, nullptr, nullptr, perm, out + 3 * NPTS, nullptr);
}

// Round 7
// 179.108 us; speedup vs baseline: 1.1125x; 1.1123x over previous
//
#include <hip/hip_runtime.h>
#include <hip/hip_fp16.h>
#include <math.h>

// SPAIRPointFeatureNetwork on MI355X.
//   h_{p,j} = Q[j] - G[p];  celu monotonic => segmax(celu(h)) = celu(max_j Q[j] - G[p]).
// Per-edge work = gather fp16 Q row + packed-fp16 running max.
//
// R6 post-mortem: three orthogonal memory-path fixes (coalescing, cell-sort,
// explicit MLP) were all ~neutral => edge kernels were NOT the limiter; the
// ~10us/dispatch launch gap x 13 kernels was. R7: drop the sort (net-negative)
// and fuse edge+finish per layer via LDS staging -> 4 dispatches total.

#define NPTS 65536
#define KNBR 64

__device__ __forceinline__ float celu1(float x) {
    return x > 0.0f ? x : (__expf(x) - 1.0f);
}

__device__ __forceinline__ unsigned pkmax(unsigned a, unsigned b) {
    unsigned d;
    asm("v_pk_max_f16 %0, %1, %2" : "=v"(d) : "v"(a), "v"(b));
    return d;
}

__device__ __forceinline__ unsigned pack2(float a, float b) {
    __half2 h = __floats2half2_rn(a, b);
    return *(unsigned*)&h;
}

// prep: Q1 (fp16) from pos, pos copy to d_out, zero batch tail.
__global__ __launch_bounds__(256) void k_prep(
    const float* __restrict__ pos,
    const float* __restrict__ w1a,   // 6 x 8
    const float* __restrict__ b1a,   // 8
    __half* __restrict__ q1,         // N x 8 (fp16)
    float* __restrict__ dout,
    int out_size)
{
    int t = blockIdx.x * 256 + threadIdx.x;
    if (t >= NPTS) return;
    float p0 = pos[3 * t + 0];
    float p1 = pos[3 * t + 1];
    float p2 = pos[3 * t + 2];
    dout[3 * t + 0] = p0;
    dout[3 * t + 1] = p1;
    dout[3 * t + 2] = p2;
    float q[8];
#pragma unroll
    for (int c = 0; c < 8; ++c) {
        float a = b1a[c];
        a = fmaf(p0, w1a[0 * 8 + c] + w1a[3 * 8 + c], a);
        a = fmaf(p1, w1a[1 * 8 + c] + w1a[4 * 8 + c], a);
        a = fmaf(p2, w1a[2 * 8 + c] + w1a[5 * 8 + c], a);
        q[c] = a;
    }
    uint4 pk;
    pk.x = pack2(q[0], q[1]);
    pk.y = pack2(q[2], q[3]);
    pk.z = pack2(q[4], q[5]);
    pk.w = pack2(q[6], q[7]);
    *(uint4*)(q1 + 8 * t) = pk;
    for (int j = 35 * NPTS + t; j < out_size; j += NPTS)
        dout[j] = 0.0f;
}

// One fused layer: edge gather+max (R6 structure) -> m staged in LDS ->
// per-point finish (threads 0..63) -> qnext (fp16) or final x.
// Block = 256 threads = 4 waves, handles 64 points.
template <int FH, int FOUT, int FHN, bool WRITEX>
__global__ __launch_bounds__(256) void k_layer(
    const __half* __restrict__ q,    // N x FH (fp16)
    const int* __restrict__ idx,     // N x 64 (int32)
    const float* __restrict__ pos,
    const float* __restrict__ wap,   // 3 x FH  (dpos rows of this layer's wa)
    const float* __restrict__ wb,    // FH x FOUT
    const float* __restrict__ bb,    // FOUT
    const float* __restrict__ wan,   // (FOUT+3) x FHN or null
    const float* __restrict__ ban,   // FHN or null
    float* __restrict__ xout,        // x region base (only if WRITEX)
    __half* __restrict__ qnext)      // N x FHN fp16 (only if FHN>0)
{
    constexpr int SL  = FH / 8;      // 16B slice-lanes per row (1,2,4)
    constexpr int LPP = SL * 8;      // lanes per point (8,16,32)
    constexpr int PPW = 64 / LPP;    // points per wave per iter (8,4,2)
    constexpr int NIT = 64 / (4 * PPW);  // iters so block covers 64 points

    __shared__ uint4 m_lds[64 * SL]; // 64 points x FH halfs

    int w  = threadIdx.x >> 6;
    int l  = threadIdx.x & 63;
    int pl = l / LPP;
    int u  = l % LPP;
    int c  = u % SL;                 // 16B slice within row
    int g  = u / SL;                 // edge group 0..7 (8 edges each)
    int pbase = blockIdx.x * 64;

#pragma unroll
    for (int it = 0; it < NIT; ++it) {
        int lp = it * (4 * PPW) + w * PPW + pl;   // local point 0..63
        int p  = pbase + lp;
        const uint4* ip = (const uint4*)(idx + p * KNBR + g * 8);
        uint4 i0 = ip[0];
        uint4 i1 = ip[1];
        // 8 independent row-slice loads, all issued before first use
        uint4 v[8];
        v[0] = *(const uint4*)(q + (int)i0.x * FH + c * 8);
        v[1] = *(const uint4*)(q + (int)i0.y * FH + c * 8);
        v[2] = *(const uint4*)(q + (int)i0.z * FH + c * 8);
        v[3] = *(const uint4*)(q + (int)i0.w * FH + c * 8);
        v[4] = *(const uint4*)(q + (int)i1.x * FH + c * 8);
        v[5] = *(const uint4*)(q + (int)i1.y * FH + c * 8);
        v[6] = *(const uint4*)(q + (int)i1.z * FH + c * 8);
        v[7] = *(const uint4*)(q + (int)i1.w * FH + c * 8);

        unsigned ax = 0xFC00FC00u, ay = 0xFC00FC00u, az = 0xFC00FC00u, aw = 0xFC00FC00u;
#pragma unroll
        for (int k = 0; k < 8; ++k) {
            ax = pkmax(ax, v[k].x);
            ay = pkmax(ay, v[k].y);
            az = pkmax(az, v[k].z);
            aw = pkmax(aw, v[k].w);
        }
        // butterfly across the 8 edge groups (strides SL..4SL stay in-point)
#pragma unroll
        for (int st = SL; st < LPP; st <<= 1) {
            ax = pkmax(ax, (unsigned)__shfl_xor((int)ax, st, 64));
            ay = pkmax(ay, (unsigned)__shfl_xor((int)ay, st, 64));
            az = pkmax(az, (unsigned)__shfl_xor((int)az, st, 64));
            aw = pkmax(aw, (unsigned)__shfl_xor((int)aw, st, 64));
        }
        if (g == 0) {
            uint4 r; r.x = ax; r.y = ay; r.z = az; r.w = aw;
            m_lds[lp * SL + c] = r;
        }
    }
    __syncthreads();

    if (threadIdx.x < 64) {
        int lt = threadIdx.x;
        int p  = pbase + lt;
        float p0 = pos[3 * p + 0];
        float p1 = pos[3 * p + 1];
        float p2 = pos[3 * p + 2];

        float h[FH];
#pragma unroll
        for (int s = 0; s < SL; ++s) {
            uint4 vv = m_lds[lt * SL + s];
            unsigned w4[4] = {vv.x, vv.y, vv.z, vv.w};
#pragma unroll
            for (int k = 0; k < 4; ++k) {
                float2 f = __half22float2(*(__half2*)&w4[k]);
                h[s * 8 + k * 2 + 0] = f.x;
                h[s * 8 + k * 2 + 1] = f.y;
            }
        }
#pragma unroll
        for (int ch = 0; ch < FH; ++ch) {
            float gg = p0 * wap[ch] + p1 * wap[FH + ch] + p2 * wap[2 * FH + ch];
            h[ch] = celu1(h[ch] - gg);
        }
        float x[FOUT];
#pragma unroll
        for (int c2 = 0; c2 < FOUT; ++c2) {
            float a = bb[c2];
#pragma unroll
            for (int ch = 0; ch < FH; ++ch)
                a = fmaf(h[ch], wb[ch * FOUT + c2], a);
            x[c2] = celu1(a);
        }
        if constexpr (WRITEX) {
            float4* xo = (float4*)(xout + (long long)p * FOUT);
#pragma unroll
            for (int c4 = 0; c4 < FOUT / 4; ++c4)
                xo[c4] = make_float4(x[4 * c4 + 0], x[4 * c4 + 1], x[4 * c4 + 2], x[4 * c4 + 3]);
        }
        if constexpr (FHN > 0) {
            float qn[FHN];
#pragma unroll
            for (int cn = 0; cn < FHN; ++cn) {
                float a = ban[cn];
#pragma unroll
                for (int c2 = 0; c2 < FOUT; ++c2)
                    a = fmaf(x[c2], wan[c2 * FHN + cn], a);
                a = fmaf(p0, wan[(FOUT + 0) * FHN + cn], a);
                a = fmaf(p1, wan[(FOUT + 1) * FHN + cn], a);
                a = fmaf(p2, wan[(FOUT + 2) * FHN + cn], a);
                qn[cn] = a;
            }
            uint4* qo = (uint4*)(qnext + p * FHN);
#pragma unroll
            for (int s = 0; s < FHN / 8; ++s) {
                uint4 pk;
                pk.x = pack2(qn[s * 8 + 0], qn[s * 8 + 1]);
                pk.y = pack2(qn[s * 8 + 2], qn[s * 8 + 3]);
                pk.z = pack2(qn[s * 8 + 4], qn[s * 8 + 5]);
                pk.w = pack2(qn[s * 8 + 6], qn[s * 8 + 7]);
                qo[s] = pk;
            }
        }
    }
}

extern "C" void kernel_launch(void* const* d_in, const int* in_sizes, int n_in,
                              void* d_out, int out_size, void* d_ws, size_t ws_size,
                              hipStream_t stream) {
    const float* pos = (const float*)d_in[0];
    // d_in[1] rgb (unused), d_in[2] batch (zeros), d_in[3] out_index (= repeat(arange(N),K))
    const int* idx = (const int*)d_in[4];   // in_index, int32 per harness contract
    const float* w1a = (const float*)d_in[5];
    const float* b1a = (const float*)d_in[6];
    const float* w1b = (const float*)d_in[7];
    const float* b1b = (const float*)d_in[8];
    const float* w2a = (const float*)d_in[9];
    const float* b2a = (const float*)d_in[10];
    const float* w2b = (const float*)d_in[11];
    const float* b2b = (const float*)d_in[12];
    const float* w3a = (const float*)d_in[13];
    const float* b3a = (const float*)d_in[14];
    const float* w3b = (const float*)d_in[15];
    const float* b3b = (const float*)d_in[16];
    float* out = (float*)d_out;

    char* ws = (char*)d_ws;
    __half* A = (__half*)ws;                        // 4 MB max: Q1 (1MB) then Q3 (4MB)
    __half* B = (__half*)(ws + (4u << 20));         // 2 MB: Q2

    k_prep<<<NPTS / 256, 256, 0, stream>>>(pos, w1a, b1a, A, out, out_size);
    // layer 1: FH=8 -> FOUT=8, emits Q2 (16ch) into B
    k_layer<8, 8, 16, false><<<NPTS / 64, 256, 0, stream>>>(
        A, idx, pos, w1a + 3 * 8, w1b, b1b, w2a, b2a, nullptr, B);
    // layer 2: FH=16 -> FOUT=16, emits Q3 (32ch) into A
    k_layer<16, 16, 32, false><<<NPTS / 64, 256, 0, stream>>>(
        B, idx, pos, w2a + 8 * 16, w2b, b2b, w3a, b3a, nullptr, A);
    // layer 3: FH=32 -> FOUT=32, writes final x into d_out
    k_layer<32, 32, 0, true><<<NPTS / 64, 256, 0, stream>>>(
        A, idx, pos, w3a + 16 * 32, w3b, b3b, nullptr, nullptr, out + 3 * NPTS, nullptr);
}